// Round 11
// baseline (13901.141 us; speedup 1.0000x reference)
//
#include <hip/hip_runtime.h>

#define T_STEPS 100
#define IC      21
#define NS      7
#define CF      64
#define HID     128
#define EPS     1e-5f

// ---------------- ws layout (float offsets) ----------------
#define OFF_W0FH   0           // [512][448] bf16 hi (elements), permuted k=p*64+oc
#define OFF_W0FL   114688
#define OFF_W0BH   229376
#define OFF_W0BL   344064
#define OFF_W1FBH  458752      // [512][256]: k<128 bf16hi | k>=128 f16
#define OFF_W1FBL  524288      // [512][256]: k<128 bf16lo | k>=128 zero
#define OFF_W1BBH  589824
#define OFF_W1BBL  655360
#define OFF_W1T    720896      // 4032
#define OFF_W2T    724928      // 12288
#define OFF_SCALE1 737216
#define OFF_SHIFT1 737280
#define OFF_SCALE2 737344
#define OFF_SHIFT2 737408
#define OFF_BIASL0 737472      // fwd 512 | bwd 512
#define OFF_BIAS1F 738496
#define OFF_BIAS1B 739008
#define PARAM_END  739520
#define OFF_H1F    739520      // [512][128] f32
#define OFF_XP1B   805056      // [512][512] f32
#define OFF_STATE  1067200     // 6 x [512][128] f32 (h0b,c0b,h0f,c0f,h1f,c1f)
#define ZERO_TOTAL 393216
#define OFF_SEQ1B  1460416     // [100][512][128] f16 (3276800 floats)
#define OFF_DYN    4737216     // dynamic: cnnH|cnnL | xpre | seqfH|seqfL = 557056/TC

#define NB_PREP    1441792     // 16-bit weight-plane elements
#define NF_PREP    411840      // float elements

typedef __attribute__((ext_vector_type(8))) short short8;
typedef __attribute__((ext_vector_type(8))) _Float16 half8;
typedef __attribute__((ext_vector_type(4))) float f32x4;

__device__ __forceinline__ float sigmoidf_(float x) { return 1.0f / (1.0f + __expf(-x)); }
__device__ __forceinline__ float tanhf_(float x)    { return 2.0f / (1.0f + __expf(-2.0f * x)) - 1.0f; }

__device__ __forceinline__ unsigned short f2bf_rn(float f) {
    union { float f; unsigned int u; } v; v.f = f;
    unsigned int u = v.u;
    return (unsigned short)((u + 0x7FFFu + ((u >> 16) & 1u)) >> 16);
}
__device__ __forceinline__ float bf2f(unsigned short h) {
    union { unsigned int u; float f; } v; v.u = ((unsigned int)h) << 16;
    return v.f;
}
__device__ __forceinline__ unsigned short f2h_u(float f) {
    union { _Float16 h; unsigned short u; } v; v.h = (_Float16)f; return v.u;
}

__device__ __forceinline__ void gload16(const void* g, void* l) {
    __builtin_amdgcn_global_load_lds(
        (const __attribute__((address_space(1))) unsigned int*)g,
        (__attribute__((address_space(3))) unsigned int*)l, 16, 0, 0);
}

// ---------------- prep (proven) ----------------
__global__ void prep_kernel(
    const float* __restrict__ c1w, const float* __restrict__ c1b,
    const float* __restrict__ g1, const float* __restrict__ b1,
    const float* __restrict__ m1, const float* __restrict__ v1,
    const float* __restrict__ c2w, const float* __restrict__ c2b,
    const float* __restrict__ g2, const float* __restrict__ b2,
    const float* __restrict__ m2, const float* __restrict__ v2,
    const float* __restrict__ wih0f, const float* __restrict__ wih0b,
    const float* __restrict__ wih1f, const float* __restrict__ wih1b,
    const float* __restrict__ bih0f, const float* __restrict__ bhh0f,
    const float* __restrict__ bih0b, const float* __restrict__ bhh0b,
    const float* __restrict__ bih1f, const float* __restrict__ bhh1f,
    const float* __restrict__ bih1b, const float* __restrict__ bhh1b,
    float* __restrict__ ws)
{
    unsigned short* wsH = (unsigned short*)ws;
    int stride = gridDim.x * blockDim.x;
    for (int i = blockIdx.x * blockDim.x + threadIdx.x;
         i < NB_PREP + NF_PREP; i += stride) {
        if (i < 917504) {                       // wih0 f/b, 4 planes, permuted
            int plane = i / 229376;             // 0 FH 1 FL 2 BH 3 BL
            int ii = i - plane * 229376;
            int n = ii / 448, kk = ii - n * 448;
            int p = kk >> 6, oc = kk & 63;
            const float* src = (plane < 2) ? wih0f : wih0b;
            float val = src[n * 448 + oc * 7 + p];
            int base = (plane == 0) ? OFF_W0FH : (plane == 1) ? OFF_W0FL
                     : (plane == 2) ? OFF_W0BH : OFF_W0BL;
            unsigned short hi = f2bf_rn(val);
            wsH[(size_t)base * 2 + ii] = (plane & 1) ? f2bf_rn(val - bf2f(hi)) : hi;
        } else if (i < NB_PREP) {               // wih1 f/b hybrid planes
            int e = i - 917504;
            int plane = e / 131072;             // 0 FBH 1 FBL 2 BBH 3 BBL
            int ii = e - plane * 131072;
            int n = ii >> 8, k = ii & 255;
            const float* src = (plane < 2) ? wih1f : wih1b;
            float val = src[n * 256 + k];
            int base = (plane == 0) ? OFF_W1FBH : (plane == 1) ? OFF_W1FBL
                     : (plane == 2) ? OFF_W1BBH : OFF_W1BBL;
            unsigned short outv;
            if (k < 128) {
                unsigned short hi = f2bf_rn(val);
                outv = (plane & 1) ? f2bf_rn(val - bf2f(hi)) : hi;
            } else {
                outv = (plane & 1) ? (unsigned short)0 : f2h_u(val);
            }
            wsH[(size_t)base * 2 + ii] = outv;
        } else {
            int j = i - NB_PREP;
            if (j < 4032) {
                int oc = j & 63, w = j >> 6;
                ws[OFF_W1T + j] = c1w[oc * 63 + w];
            } else if (j < 16320) {
                int jj = j - 4032;
                int oc = jj & 63, w = jj >> 6;
                ws[OFF_W2T + jj] = c2w[oc * 192 + w];
            } else if (j < 16384) {
                int oc = j - 16320;
                ws[OFF_SCALE1 + oc] = g1[oc] * rsqrtf(v1[oc] + EPS);
            } else if (j < 16448) {
                int oc = j - 16384;
                float inv = g1[oc] * rsqrtf(v1[oc] + EPS);
                ws[OFF_SHIFT1 + oc] = c1b[oc] * inv + b1[oc] - m1[oc] * inv;
            } else if (j < 16512) {
                int oc = j - 16448;
                ws[OFF_SCALE2 + oc] = g2[oc] * rsqrtf(v2[oc] + EPS);
            } else if (j < 16576) {
                int oc = j - 16512;
                float inv = g2[oc] * rsqrtf(v2[oc] + EPS);
                ws[OFF_SHIFT2 + oc] = c2b[oc] * inv + b2[oc] - m2[oc] * inv;
            } else if (j < 17600) {
                int n = j - 16576;
                ws[OFF_BIASL0 + n] = (n < 512) ? (bih0f[n] + bhh0f[n])
                                               : (bih0b[n - 512] + bhh0b[n - 512]);
            } else if (j < 18112) {
                int n = j - 17600;
                ws[OFF_BIAS1F + n] = bih1f[n] + bhh1f[n];
            } else if (j < 18624) {
                int n = j - 18112;
                ws[OFF_BIAS1B + n] = bih1b[n] + bhh1b[n];
            } else {
                ws[OFF_STATE + (j - 18624)] = 0.f;
            }
        }
    }
}

// ---------------- fused CNN, R4-proven 256-thread version ----------------
// block: 16 samples, 256 threads = oc(64) x sq(4); out [row][p*64+oc] bf16 hi/lo
__global__ __launch_bounds__(256) void cnn_kernel(
    const float* __restrict__ x, const float* __restrict__ ws,
    unsigned short* __restrict__ outH, unsigned short* __restrict__ outL, int t0)
{
    __shared__ __align__(16) float xs[16][IC][12];
    __shared__ __align__(16) float y1[16][9][64];

    int tid = threadIdx.x;
    int oc = tid & 63, sq = tid >> 6;
    int rbase = blockIdx.x * 16;
    int tt = rbase >> 9;
    int b0 = rbase & 511;
    int t = t0 + tt;

    for (int i = tid; i < 16 * IC * 12; i += 256) ((float*)xs)[i] = 0.f;
    __syncthreads();
    for (int idx = tid; idx < 16 * 147; idx += 256) {
        int s = idx / 147, e = idx - s * 147;
        int ic = e / 7, px = e - ic * 7;
        xs[s][ic][px + 1] = x[((size_t)(b0 + s) * T_STEPS + t) * 147 + e];
    }
    __syncthreads();

    const float* w1t = ws + OFF_W1T;
    float acc1[4][7];
#pragma unroll
    for (int si = 0; si < 4; si++)
#pragma unroll
        for (int p = 0; p < 7; p++) acc1[si][p] = 0.f;

    for (int ic = 0; ic < IC; ic++) {
        float w0 = w1t[(ic * 3 + 0) * 64 + oc];
        float w1 = w1t[(ic * 3 + 1) * 64 + oc];
        float w2 = w1t[(ic * 3 + 2) * 64 + oc];
#pragma unroll
        for (int si = 0; si < 4; si++) {
            int s = 4 * sq + si;
            const float* xr = &xs[s][ic][0];
            float4 xa = *(const float4*)xr;
            float4 xb = *(const float4*)(xr + 4);
            float x8 = xr[8];
            float xv[9] = {xa.x, xa.y, xa.z, xa.w, xb.x, xb.y, xb.z, xb.w, x8};
#pragma unroll
            for (int p = 0; p < 7; p++)
                acc1[si][p] += w0 * xv[p] + w1 * xv[p + 1] + w2 * xv[p + 2];
        }
    }
    for (int i = tid; i < 2048; i += 256) {
        int s = i >> 7, row = ((i >> 6) & 1) ? 8 : 0, o2 = i & 63;
        y1[s][row][o2] = 0.f;
    }
    {
        float sc = ws[OFF_SCALE1 + oc], sh = ws[OFF_SHIFT1 + oc];
#pragma unroll
        for (int si = 0; si < 4; si++) {
            int s = 4 * sq + si;
#pragma unroll
            for (int p = 0; p < 7; p++) {
                float v = acc1[si][p] * sc + sh;
                y1[s][p + 1][oc] = v > 0.f ? v : 0.f;
            }
        }
    }
    __syncthreads();

    const float* w2t = ws + OFF_W2T;
    float acc2[4][7];
#pragma unroll
    for (int si = 0; si < 4; si++)
#pragma unroll
        for (int p = 0; p < 7; p++) acc2[si][p] = 0.f;

    for (int c4 = 0; c4 < 16; c4++) {
        float wv[12];
#pragma unroll
        for (int cc = 0; cc < 4; cc++)
#pragma unroll
            for (int k = 0; k < 3; k++)
                wv[cc * 3 + k] = w2t[((c4 * 4 + cc) * 3 + k) * 64 + oc];
#pragma unroll
        for (int si = 0; si < 4; si++) {
            int s = 4 * sq + si;
            float4 yv[9];
#pragma unroll
            for (int r = 0; r < 9; r++) yv[r] = *(const float4*)&y1[s][r][c4 * 4];
#pragma unroll
            for (int p = 0; p < 7; p++) {
                float a = 0.f;
#pragma unroll
                for (int k = 0; k < 3; k++) {
                    float4 yy = yv[p + k];
                    a += wv[0 * 3 + k] * yy.x + wv[1 * 3 + k] * yy.y
                       + wv[2 * 3 + k] * yy.z + wv[3 * 3 + k] * yy.w;
                }
                acc2[si][p] += a;
            }
        }
    }
    {
        float sc = ws[OFF_SCALE2 + oc], sh = ws[OFF_SHIFT2 + oc];
#pragma unroll
        for (int si = 0; si < 4; si++) {
            int s = 4 * sq + si;
#pragma unroll
            for (int p = 0; p < 7; p++) {
                float v = acc2[si][p] * sc + sh;
                v = v > 0.f ? v : 0.f;
                unsigned short hi = f2bf_rn(v);
                unsigned short lo = f2bf_rn(v - bf2f(hi));
                size_t o = (size_t)(rbase + s) * 448 + p * 64 + oc;
                outH[o] = hi; outL[o] = lo;
            }
        }
    }
}

// ---------------- hybrid split-bf16 / f16 MFMA GEMM, plain args ----------------
// out[m][n] = sum_k A(m,k)*Bt[n,k] + bias[n]; N=512 (grid.y=4); tile 128x128, BK=32
// k<K0: split-bf16 (A0h+A0l, Bh+Bl, 3 MFMA); k>=K0: f16 (A1, Bh f16 cols, 1 MFMA)
__global__ __launch_bounds__(256, 2) void mgemm(
    const unsigned short* __restrict__ A0h, const unsigned short* __restrict__ A0l,
    int lda0, int K0,
    const _Float16* __restrict__ A1, int lda1,
    const unsigned short* __restrict__ Bh, const unsigned short* __restrict__ Bl,
    const float* __restrict__ bias, float* __restrict__ out, int K)
{
    __shared__ __align__(16) unsigned short lAh[128 * 32];
    __shared__ __align__(16) unsigned short lAl[128 * 32];
    __shared__ __align__(16) unsigned short lBh[128 * 32];
    __shared__ __align__(16) unsigned short lBl[128 * 32];

    int tid = threadIdx.x;
    int m0 = blockIdx.x * 128, n0 = blockIdx.y * 128;
    int l = tid & 63, w = tid >> 6;
    int wm = w >> 1, wn = w & 1;
    int lr = l & 15, lk = l >> 4;

    int srow = w * 16 + (l >> 2);        // 0..63 within half
    int skoff = (l & 3) * 8;             // 16-bit units

    f32x4 acc[4][4];
#pragma unroll
    for (int i = 0; i < 4; i++)
#pragma unroll
        for (int j = 0; j < 4; j++) acc[i][j] = (f32x4){0.f, 0.f, 0.f, 0.f};

    for (int kt = 0; kt < K; kt += 32) {
        bool seg0 = (kt < K0);
        __syncthreads();
#pragma unroll
        for (int hh = 0; hh < 2; hh++) {
            size_t arow = (size_t)(m0 + hh * 64 + srow);
            size_t brow = (size_t)(n0 + hh * 64 + srow);
            char* dA  = (char*)lAh + hh * 4096 + w * 1024;
            char* dAl = (char*)lAl + hh * 4096 + w * 1024;
            char* dB  = (char*)lBh + hh * 4096 + w * 1024;
            char* dBl = (char*)lBl + hh * 4096 + w * 1024;
            if (seg0) {
                gload16(A0h + arow * lda0 + kt + skoff, dA);
                gload16(A0l + arow * lda0 + kt + skoff, dAl);
                gload16(Bl + brow * K + kt + skoff, dBl);
            } else {
                gload16(A1 + arow * lda1 + (kt - K0) + skoff, dA);
            }
            gload16(Bh + brow * K + kt + skoff, dB);
        }
        __syncthreads();

        if (seg0) {
            short8 fah[4], fal[4], fbh[4], fbl[4];
#pragma unroll
            for (int mf = 0; mf < 4; mf++) {
                int row = wm * 64 + mf * 16 + lr;
                fah[mf] = *(const short8*)&lAh[row * 32 + lk * 8];
                fal[mf] = *(const short8*)&lAl[row * 32 + lk * 8];
            }
#pragma unroll
            for (int nf = 0; nf < 4; nf++) {
                int row = wn * 64 + nf * 16 + lr;
                fbh[nf] = *(const short8*)&lBh[row * 32 + lk * 8];
                fbl[nf] = *(const short8*)&lBl[row * 32 + lk * 8];
            }
#pragma unroll
            for (int mf = 0; mf < 4; mf++)
#pragma unroll
                for (int nf = 0; nf < 4; nf++) {
                    acc[mf][nf] = __builtin_amdgcn_mfma_f32_16x16x32_bf16(
                        fah[mf], fbh[nf], acc[mf][nf], 0, 0, 0);
                    acc[mf][nf] = __builtin_amdgcn_mfma_f32_16x16x32_bf16(
                        fah[mf], fbl[nf], acc[mf][nf], 0, 0, 0);
                    acc[mf][nf] = __builtin_amdgcn_mfma_f32_16x16x32_bf16(
                        fal[mf], fbh[nf], acc[mf][nf], 0, 0, 0);
                }
        } else {
            half8 fah[4], fbh[4];
#pragma unroll
            for (int mf = 0; mf < 4; mf++) {
                int row = wm * 64 + mf * 16 + lr;
                fah[mf] = *(const half8*)&lAh[row * 32 + lk * 8];
            }
#pragma unroll
            for (int nf = 0; nf < 4; nf++) {
                int row = wn * 64 + nf * 16 + lr;
                fbh[nf] = *(const half8*)&lBh[row * 32 + lk * 8];
            }
#pragma unroll
            for (int mf = 0; mf < 4; mf++)
#pragma unroll
                for (int nf = 0; nf < 4; nf++)
                    acc[mf][nf] = __builtin_amdgcn_mfma_f32_16x16x32_f16(
                        fah[mf], fbh[nf], acc[mf][nf], 0, 0, 0);
        }
    }

#pragma unroll
    for (int nf = 0; nf < 4; nf++) {
        int gcol = n0 + wn * 64 + nf * 16 + lr;
        float bv = bias[gcol];
#pragma unroll
        for (int mf = 0; mf < 4; mf++) {
            int grow = m0 + wm * 64 + mf * 16 + lk * 4;
#pragma unroll
            for (int q = 0; q < 4; q++)
                out[(size_t)(grow + q) * 512 + gcol] = acc[mf][nf][q] + bv;
        }
    }
}

// ---------------- LSTM scan, R4-proven (plain args, template modes) ----------------
// OUTMODE 0: seqf bf16 HL chunk-local; 1: seq1b f16 global-t; 2: f32 h at t==99
template <int OUTMODE, int REV>
__global__ __launch_bounds__(512) void lstm_scan(
    const float* __restrict__ Xpre, const float* __restrict__ whh,
    float* __restrict__ state_h, float* __restrict__ state_c,
    unsigned short* __restrict__ outH, unsigned short* __restrict__ outL,
    _Float16* __restrict__ out16, float* __restrict__ outF, int t0, int TC)
{
    int r0 = blockIdx.x * 2;
    int g = threadIdx.x;

    __shared__ __align__(16) float h_lds[2][128];
    __shared__ float c_lds[2][128];
    __shared__ float g_lds[2][512];

    float w[128];
#pragma unroll
    for (int k = 0; k < 128; k += 4) {
        float4 wv = *(const float4*)&whh[(size_t)g * 128 + k];
        w[k] = wv.x; w[k + 1] = wv.y; w[k + 2] = wv.z; w[k + 3] = wv.w;
    }
    if (g < 256) {
        int r = g >> 7, j = g & 127;
        h_lds[r][j] = state_h[(size_t)(r0 + r) * 128 + j];
        c_lds[r][j] = state_c[(size_t)(r0 + r) * 128 + j];
    }
    __syncthreads();

    for (int s = 0; s < TC; s++) {
        int tt = REV ? (TC - 1 - s) : s;
        float acc0 = Xpre[((size_t)tt * 512 + r0 + 0) * 512 + g];
        float acc1 = Xpre[((size_t)tt * 512 + r0 + 1) * 512 + g];
#pragma unroll
        for (int k = 0; k < 128; k += 4) {
            float4 h0 = *(const float4*)&h_lds[0][k];
            float4 h1 = *(const float4*)&h_lds[1][k];
            acc0 += w[k] * h0.x + w[k + 1] * h0.y + w[k + 2] * h0.z + w[k + 3] * h0.w;
            acc1 += w[k] * h1.x + w[k + 1] * h1.y + w[k + 2] * h1.z + w[k + 3] * h1.w;
        }
        g_lds[0][g] = acc0;
        g_lds[1][g] = acc1;
        __syncthreads();
        if (g < 256) {
            int r = g >> 7, j = g & 127;
            float gi = sigmoidf_(g_lds[r][j]);
            float gf = sigmoidf_(g_lds[r][128 + j]);
            float gg = tanhf_(g_lds[r][256 + j]);
            float go = sigmoidf_(g_lds[r][384 + j]);
            float c = gf * c_lds[r][j] + gi * gg;
            c_lds[r][j] = c;
            float h = go * tanhf_(c);
            h_lds[r][j] = h;
            if (OUTMODE == 0) {
                size_t idx = ((size_t)tt * 512 + r0 + r) * 128 + j;
                unsigned short hi = f2bf_rn(h);
                outH[idx] = hi;
                outL[idx] = f2bf_rn(h - bf2f(hi));
            } else if (OUTMODE == 1) {
                size_t idx = ((size_t)(t0 + tt) * 512 + r0 + r) * 128 + j;
                out16[idx] = (_Float16)h;
            } else if (t0 + tt == T_STEPS - 1) {
                outF[(size_t)(r0 + r) * 128 + j] = h;
            }
        }
        __syncthreads();
    }

    if (g < 256) {
        int r = g >> 7, j = g & 127;
        state_h[(size_t)(r0 + r) * 128 + j] = h_lds[r][j];
        state_c[(size_t)(r0 + r) * 128 + j] = c_lds[r][j];
    }
}

// ---------------- final: layer1-bwd single step + FC head ----------------
__global__ __launch_bounds__(128) void final_kernel(
    const float* __restrict__ h1f, const float* __restrict__ xp1b,
    const float* __restrict__ fc1w, const float* __restrict__ fc1b,
    const float* __restrict__ fc2w, const float* __restrict__ fc2b,
    float* __restrict__ out)
{
    int b = blockIdx.x, tid = threadIdx.x;
    __shared__ float last[256];
    __shared__ float f1[64];
    {
        int j = tid;
        float gi = sigmoidf_(xp1b[(size_t)b * 512 + j]);
        float gg = tanhf_(xp1b[(size_t)b * 512 + 256 + j]);
        float go = sigmoidf_(xp1b[(size_t)b * 512 + 384 + j]);
        float c = gi * gg;                  // h0 = c0 = 0
        last[128 + j] = go * tanhf_(c);
        last[j] = h1f[(size_t)b * 128 + j];
    }
    __syncthreads();
    if (tid < 64) {
        float a = fc1b[tid];
        for (int k = 0; k < 256; k++) a += last[k] * fc1w[tid * 256 + k];
        f1[tid] = a > 0.f ? a : 0.f;
    }
    __syncthreads();
    if (tid < 2) {
        float a = fc2b[tid];
        for (int k = 0; k < 64; k++) a += f1[k] * fc2w[tid * 64 + k];
        out[b * 2 + tid] = a;
    }
}

extern "C" void kernel_launch(void* const* d_in, const int* in_sizes, int n_in,
                              void* d_out, int out_size, void* d_ws, size_t ws_size,
                              hipStream_t stream)
{
    const float* x     = (const float*)d_in[0];
    const float* c1w   = (const float*)d_in[1];
    const float* c1b   = (const float*)d_in[2];
    const float* g1    = (const float*)d_in[3];
    const float* b1    = (const float*)d_in[4];
    const float* m1    = (const float*)d_in[5];
    const float* v1    = (const float*)d_in[6];
    const float* c2w   = (const float*)d_in[7];
    const float* c2b   = (const float*)d_in[8];
    const float* g2    = (const float*)d_in[9];
    const float* b2    = (const float*)d_in[10];
    const float* m2    = (const float*)d_in[11];
    const float* v2    = (const float*)d_in[12];
    const float* wih0f = (const float*)d_in[13];
    const float* whh0f = (const float*)d_in[14];
    const float* bih0f = (const float*)d_in[15];
    const float* bhh0f = (const float*)d_in[16];
    const float* wih0b = (const float*)d_in[17];
    const float* whh0b = (const float*)d_in[18];
    const float* bih0b = (const float*)d_in[19];
    const float* bhh0b = (const float*)d_in[20];
    const float* wih1f = (const float*)d_in[21];
    const float* whh1f = (const float*)d_in[22];
    const float* bih1f = (const float*)d_in[23];
    const float* bhh1f = (const float*)d_in[24];
    const float* wih1b = (const float*)d_in[25];
    const float* bih1b = (const float*)d_in[27];
    const float* bhh1b = (const float*)d_in[28];
    const float* fc1w  = (const float*)d_in[29];
    const float* fc1b  = (const float*)d_in[30];
    const float* fc2w  = (const float*)d_in[31];
    const float* fc2b  = (const float*)d_in[32];

    float* ws  = (float*)d_ws;
    unsigned short* wsH = (unsigned short*)d_ws;
    float* out = (float*)d_out;

    // TC=1 FORCED: R4's 800-dispatch structure is the proven-fast regime
    // (R4=1369us @TC=1 vs R6=2424us @TC=5 with these same kernel bodies).
    const int TC = 1;
    const int NCH = T_STEPS;   // 100

    unsigned short* cnnH = wsH + (size_t)OFF_DYN * 2;       // [512][448] bf16 x2
    unsigned short* cnnL = cnnH + (size_t)TC * 229376;
    float* xpre = ws + OFF_DYN + (size_t)TC * 229376;       // f32 [512][512]
    unsigned short* seqfH = (unsigned short*)(xpre + (size_t)TC * 262144);
    unsigned short* seqfL = seqfH + (size_t)TC * 65536;
    _Float16* seq1b = (_Float16*)(ws + OFF_SEQ1B);          // [100*512][128] f16

    const unsigned short* W0FH = wsH + (size_t)OFF_W0FH * 2;
    const unsigned short* W0FL = wsH + (size_t)OFF_W0FL * 2;
    const unsigned short* W0BH = wsH + (size_t)OFF_W0BH * 2;
    const unsigned short* W0BL = wsH + (size_t)OFF_W0BL * 2;
    const unsigned short* W1FBH = wsH + (size_t)OFF_W1FBH * 2;
    const unsigned short* W1FBL = wsH + (size_t)OFF_W1FBL * 2;
    const unsigned short* W1BBH = wsH + (size_t)OFF_W1BBH * 2;
    const unsigned short* W1BBL = wsH + (size_t)OFF_W1BBL * 2;

    float* st = ws + OFF_STATE;   // h0b,c0b,h0f,c0f,h1f,c1f

    // 1. prep
    hipLaunchKernelGGL(prep_kernel, dim3(7241), dim3(256), 0, stream,
                       c1w, c1b, g1, b1, m1, v1, c2w, c2b, g2, b2, m2, v2,
                       wih0f, wih0b, wih1f, wih1b,
                       bih0f, bhh0f, bih0b, bhh0b, bih1f, bhh1f, bih1b, bhh1b, ws);

    // 2. phase 1: layer-0 backward, steps in reverse time order
    for (int j = 0; j < NCH; j++) {
        int t0 = (NCH - 1 - j) * TC;
        hipLaunchKernelGGL(cnn_kernel, dim3(TC * 32), dim3(256), 0, stream,
                           x, ws, cnnH, cnnL, t0);
        hipLaunchKernelGGL(mgemm, dim3(TC * 4, 4), dim3(256), 0, stream,
                           cnnH, cnnL, 448, 448, (const _Float16*)nullptr, 0,
                           W0BH, W0BL, ws + OFF_BIASL0 + 512, xpre, 448);
        hipLaunchKernelGGL((lstm_scan<1, 1>), dim3(256), dim3(512), 0, stream,
                           xpre, whh0b, st, st + 65536,
                           (unsigned short*)nullptr, (unsigned short*)nullptr,
                           seq1b, (float*)nullptr, t0, TC);
    }

    // 3. phase 2: layer-0 forward then layer-1 forward, per step (R4 order)
    for (int i = 0; i < NCH; i++) {
        int t0 = i * TC;
        hipLaunchKernelGGL(cnn_kernel, dim3(TC * 32), dim3(256), 0, stream,
                           x, ws, cnnH, cnnL, t0);
        hipLaunchKernelGGL(mgemm, dim3(TC * 4, 4), dim3(256), 0, stream,
                           cnnH, cnnL, 448, 448, (const _Float16*)nullptr, 0,
                           W0FH, W0FL, ws + OFF_BIASL0, xpre, 448);
        hipLaunchKernelGGL((lstm_scan<0, 0>), dim3(256), dim3(512), 0, stream,
                           xpre, whh0f, st + 131072, st + 196608,
                           seqfH, seqfL, (_Float16*)nullptr, (float*)nullptr, t0, TC);
        hipLaunchKernelGGL(mgemm, dim3(TC * 4, 4), dim3(256), 0, stream,
                           seqfH, seqfL, 128, 128, seq1b + (size_t)t0 * 65536, 128,
                           W1FBH, W1FBL, ws + OFF_BIAS1F, xpre, 256);
        hipLaunchKernelGGL((lstm_scan<2, 0>), dim3(256), dim3(512), 0, stream,
                           xpre, whh1f, st + 262144, st + 327680,
                           (unsigned short*)nullptr, (unsigned short*)nullptr,
                           (_Float16*)nullptr, ws + OFF_H1F, t0, TC);
    }

    // 4. layer-1 backward single step (t=99)
    hipLaunchKernelGGL(mgemm, dim3(4, 4), dim3(256), 0, stream,
                       seqfH + (size_t)(TC - 1) * 65536, seqfL + (size_t)(TC - 1) * 65536,
                       128, 128, seq1b + (size_t)99 * 65536, 128,
                       W1BBH, W1BBL, ws + OFF_BIAS1B, ws + OFF_XP1B, 256);

    // 5. final FC head
    hipLaunchKernelGGL(final_kernel, dim3(512), dim3(128), 0, stream,
                       ws + OFF_H1F, ws + OFF_XP1B, fc1w, fc1b, fc2w, fc2b, out);

    (void)in_sizes; (void)n_in; (void)out_size; (void)ws_size;
}

// Round 12
// 1365.437 us; speedup vs baseline: 10.1807x; 10.1807x over previous
//
#include <hip/hip_runtime.h>

#define T_STEPS 100
#define IC      21
#define NS      7
#define CF      64
#define HID     128
#define EPS     1e-5f

// ---------------- ws layout (float offsets) ----------------
#define OFF_W0FH   0           // [512][448] bf16 hi, permuted k=p*64+oc
#define OFF_W0FL   114688
#define OFF_W0BH   229376
#define OFF_W0BL   344064
#define OFF_W1FH   458752      // [512][256] bf16
#define OFF_W1FL   524288
#define OFF_W1BH   589824
#define OFF_W1BL   655360
#define OFF_W1T    720896      // 4032
#define OFF_W2T    724928      // 12288
#define OFF_SCALE1 737216
#define OFF_SHIFT1 737280
#define OFF_SCALE2 737344
#define OFF_SHIFT2 737408
#define OFF_BIASL0 737472      // fwd 512 | bwd 512
#define OFF_BIAS1F 738496
#define OFF_BIAS1B 739008
#define PARAM_END  739520
#define OFF_H1F    739520      // [512][128] f32
#define OFF_XP1B   805056      // [512][512] f32
#define OFF_STATE  1067200     // 6 x [512][128] f32
#define ZERO_TOTAL 393216
#define OFF_SEQ1BH 1460416     // [100][512][128] bf16 hi (3276800 floats)
#define OFF_SEQ1BL 4737216
#define OFF_DYN    8014016     // cnnH|cnnL | xprebuf | seqfH|seqfL

#define NB_PREP    1441792     // bf16 weight-plane elements
#define NF_PREP    411840      // float elements (cnn w + biases + state zero)

typedef __attribute__((ext_vector_type(8))) short short8;
typedef __attribute__((ext_vector_type(4))) float f32x4;

__device__ __forceinline__ float sigmoidf_(float x) { return 1.0f / (1.0f + __expf(-x)); }
__device__ __forceinline__ float tanhf_(float x)    { return 2.0f / (1.0f + __expf(-2.0f * x)) - 1.0f; }

__device__ __forceinline__ unsigned short f2bf_rn(float f) {
    union { float f; unsigned int u; } v; v.f = f;
    unsigned int u = v.u;
    return (unsigned short)((u + 0x7FFFu + ((u >> 16) & 1u)) >> 16);
}
__device__ __forceinline__ float bf2f(unsigned short h) {
    union { unsigned int u; float f; } v; v.u = ((unsigned int)h) << 16;
    return v.f;
}

__device__ __forceinline__ void gload16(const void* g, void* l) {
    __builtin_amdgcn_global_load_lds(
        (const __attribute__((address_space(1))) unsigned int*)g,
        (__attribute__((address_space(3))) unsigned int*)l, 16, 0, 0);
}

// ---------------- prep: weight splits/permutes + BN/bias folding + state zero ---------
__global__ void prep_kernel(
    const float* __restrict__ c1w, const float* __restrict__ c1b,
    const float* __restrict__ g1, const float* __restrict__ b1,
    const float* __restrict__ m1, const float* __restrict__ v1,
    const float* __restrict__ c2w, const float* __restrict__ c2b,
    const float* __restrict__ g2, const float* __restrict__ b2,
    const float* __restrict__ m2, const float* __restrict__ v2,
    const float* __restrict__ wih0f, const float* __restrict__ wih0b,
    const float* __restrict__ wih1f, const float* __restrict__ wih1b,
    const float* __restrict__ bih0f, const float* __restrict__ bhh0f,
    const float* __restrict__ bih0b, const float* __restrict__ bhh0b,
    const float* __restrict__ bih1f, const float* __restrict__ bhh1f,
    const float* __restrict__ bih1b, const float* __restrict__ bhh1b,
    float* __restrict__ ws)
{
    unsigned short* wsH = (unsigned short*)ws;
    int stride = gridDim.x * blockDim.x;
    for (int i = blockIdx.x * blockDim.x + threadIdx.x;
         i < NB_PREP + NF_PREP; i += stride) {
        if (i < NB_PREP) {
            // bf16 weight planes
            float val; size_t dst; bool lo;
            if (i < 917504) {                       // wih0 f/b, permuted
                int plane = i / 229376;             // 0 FH 1 FL 2 BH 3 BL
                int ii = i - plane * 229376;
                int n = ii / 448, kk = ii - n * 448;
                int p = kk >> 6, oc = kk & 63;
                const float* src = (plane < 2) ? wih0f : wih0b;
                val = src[n * 448 + oc * 7 + p];
                int base = (plane == 0) ? OFF_W0FH : (plane == 1) ? OFF_W0FL
                         : (plane == 2) ? OFF_W0BH : OFF_W0BL;
                dst = (size_t)base * 2 + ii;
                lo = (plane & 1);
            } else {                                // wih1 f/b, direct
                int e = i - 917504;
                int plane = e / 131072;
                int ii = e - plane * 131072;
                const float* src = (plane < 2) ? wih1f : wih1b;
                val = src[ii];
                int base = (plane == 0) ? OFF_W1FH : (plane == 1) ? OFF_W1FL
                         : (plane == 2) ? OFF_W1BH : OFF_W1BL;
                dst = (size_t)base * 2 + ii;
                lo = (plane & 1);
            }
            unsigned short hi = f2bf_rn(val);
            wsH[dst] = lo ? f2bf_rn(val - bf2f(hi)) : hi;
        } else {
            int j = i - NB_PREP;
            if (j < 4032) {
                int oc = j & 63, w = j >> 6;
                ws[OFF_W1T + j] = c1w[oc * 63 + w];
            } else if (j < 16320) {
                int jj = j - 4032;
                int oc = jj & 63, w = jj >> 6;
                ws[OFF_W2T + jj] = c2w[oc * 192 + w];
            } else if (j < 16384) {
                int oc = j - 16320;
                ws[OFF_SCALE1 + oc] = g1[oc] * rsqrtf(v1[oc] + EPS);
            } else if (j < 16448) {
                int oc = j - 16384;
                float inv = g1[oc] * rsqrtf(v1[oc] + EPS);
                ws[OFF_SHIFT1 + oc] = c1b[oc] * inv + b1[oc] - m1[oc] * inv;
            } else if (j < 16512) {
                int oc = j - 16448;
                ws[OFF_SCALE2 + oc] = g2[oc] * rsqrtf(v2[oc] + EPS);
            } else if (j < 16576) {
                int oc = j - 16512;
                float inv = g2[oc] * rsqrtf(v2[oc] + EPS);
                ws[OFF_SHIFT2 + oc] = c2b[oc] * inv + b2[oc] - m2[oc] * inv;
            } else if (j < 17600) {
                int n = j - 16576;
                ws[OFF_BIASL0 + n] = (n < 512) ? (bih0f[n] + bhh0f[n])
                                               : (bih0b[n - 512] + bhh0b[n - 512]);
            } else if (j < 18112) {
                int n = j - 17600;
                ws[OFF_BIAS1F + n] = bih1f[n] + bhh1f[n];
            } else if (j < 18624) {
                int n = j - 18112;
                ws[OFF_BIAS1B + n] = bih1b[n] + bhh1b[n];
            } else {
                ws[OFF_STATE + (j - 18624)] = 0.f;
            }
        }
    }
}

// ---------------- fused CNN, register-blocked, split-bf16 output ----------------
// block: 16 samples, 256 threads = oc(64) x sq(4); out layout [row][p*64+oc] bf16 hi/lo
__global__ __launch_bounds__(256) void cnn_kernel(
    const float* __restrict__ x, const float* __restrict__ ws,
    unsigned short* __restrict__ outH, unsigned short* __restrict__ outL, int t0)
{
    __shared__ __align__(16) float xs[16][IC][12];
    __shared__ __align__(16) float y1[16][9][64];

    int tid = threadIdx.x;
    int oc = tid & 63, sq = tid >> 6;
    int rbase = blockIdx.x * 16;
    int tt = rbase >> 9;
    int b0 = rbase & 511;
    int t = t0 + tt;

    for (int i = tid; i < 16 * IC * 12; i += 256) ((float*)xs)[i] = 0.f;
    __syncthreads();
    for (int idx = tid; idx < 16 * 147; idx += 256) {
        int s = idx / 147, e = idx - s * 147;
        int ic = e / 7, px = e - ic * 7;
        xs[s][ic][px + 1] = x[((size_t)(b0 + s) * T_STEPS + t) * 147 + e];
    }
    __syncthreads();

    const float* w1t = ws + OFF_W1T;
    float acc1[4][7];
#pragma unroll
    for (int si = 0; si < 4; si++)
#pragma unroll
        for (int p = 0; p < 7; p++) acc1[si][p] = 0.f;

    for (int ic = 0; ic < IC; ic++) {
        float w0 = w1t[(ic * 3 + 0) * 64 + oc];
        float w1 = w1t[(ic * 3 + 1) * 64 + oc];
        float w2 = w1t[(ic * 3 + 2) * 64 + oc];
#pragma unroll
        for (int si = 0; si < 4; si++) {
            int s = 4 * sq + si;
            const float* xr = &xs[s][ic][0];
            float4 xa = *(const float4*)xr;
            float4 xb = *(const float4*)(xr + 4);
            float x8 = xr[8];
            float xv[9] = {xa.x, xa.y, xa.z, xa.w, xb.x, xb.y, xb.z, xb.w, x8};
#pragma unroll
            for (int p = 0; p < 7; p++)
                acc1[si][p] += w0 * xv[p] + w1 * xv[p + 1] + w2 * xv[p + 2];
        }
    }
    for (int i = tid; i < 2048; i += 256) {
        int s = i >> 7, row = ((i >> 6) & 1) ? 8 : 0, o2 = i & 63;
        y1[s][row][o2] = 0.f;
    }
    {
        float sc = ws[OFF_SCALE1 + oc], sh = ws[OFF_SHIFT1 + oc];
#pragma unroll
        for (int si = 0; si < 4; si++) {
            int s = 4 * sq + si;
#pragma unroll
            for (int p = 0; p < 7; p++) {
                float v = acc1[si][p] * sc + sh;
                y1[s][p + 1][oc] = v > 0.f ? v : 0.f;
            }
        }
    }
    __syncthreads();

    const float* w2t = ws + OFF_W2T;
    float acc2[4][7];
#pragma unroll
    for (int si = 0; si < 4; si++)
#pragma unroll
        for (int p = 0; p < 7; p++) acc2[si][p] = 0.f;

    for (int c4 = 0; c4 < 16; c4++) {
        float wv[12];
#pragma unroll
        for (int cc = 0; cc < 4; cc++)
#pragma unroll
            for (int k = 0; k < 3; k++)
                wv[cc * 3 + k] = w2t[((c4 * 4 + cc) * 3 + k) * 64 + oc];
#pragma unroll
        for (int si = 0; si < 4; si++) {
            int s = 4 * sq + si;
            float4 yv[9];
#pragma unroll
            for (int r = 0; r < 9; r++) yv[r] = *(const float4*)&y1[s][r][c4 * 4];
#pragma unroll
            for (int p = 0; p < 7; p++) {
                float a = 0.f;
#pragma unroll
                for (int k = 0; k < 3; k++) {
                    float4 yy = yv[p + k];
                    a += wv[0 * 3 + k] * yy.x + wv[1 * 3 + k] * yy.y
                       + wv[2 * 3 + k] * yy.z + wv[3 * 3 + k] * yy.w;
                }
                acc2[si][p] += a;
            }
        }
    }
    {
        float sc = ws[OFF_SCALE2 + oc], sh = ws[OFF_SHIFT2 + oc];
#pragma unroll
        for (int si = 0; si < 4; si++) {
            int s = 4 * sq + si;
#pragma unroll
            for (int p = 0; p < 7; p++) {
                float v = acc2[si][p] * sc + sh;
                v = v > 0.f ? v : 0.f;
                unsigned short hi = f2bf_rn(v);
                unsigned short lo = f2bf_rn(v - bf2f(hi));
                size_t o = (size_t)(rbase + s) * 448 + p * 64 + oc;
                outH[o] = hi; outL[o] = lo;
            }
        }
    }
}

// ---------------- split-bf16 MFMA GEMM ----------------
// out[m][n] = sum_k A(m,k)*Bt[n,k] + bias[n], N=512 (grid.y=4), tile 128x128, BK=32
// A(m,k): k<K0 -> A0 planes [*, lda0]; else A1 planes [*, lda1] at k-K0
__global__ __launch_bounds__(256, 2) void mgemm(
    const unsigned short* __restrict__ A0h, const unsigned short* __restrict__ A0l,
    int lda0, int K0,
    const unsigned short* __restrict__ A1h, const unsigned short* __restrict__ A1l,
    int lda1,
    const unsigned short* __restrict__ Bh, const unsigned short* __restrict__ Bl,
    const float* __restrict__ bias, float* __restrict__ out, int K)
{
    __shared__ __align__(16) unsigned short lAh[128 * 32];
    __shared__ __align__(16) unsigned short lAl[128 * 32];
    __shared__ __align__(16) unsigned short lBh[128 * 32];
    __shared__ __align__(16) unsigned short lBl[128 * 32];

    int tid = threadIdx.x;
    int m0 = blockIdx.x * 128, n0 = blockIdx.y * 128;
    int l = tid & 63, w = tid >> 6;
    int wm = w >> 1, wn = w & 1;
    int lr = l & 15, lk = l >> 4;

    int srow = w * 16 + (l >> 2);        // 0..63 within half
    int skoff = (l & 3) * 8;             // bf16 units

    f32x4 acc[4][4];
#pragma unroll
    for (int i = 0; i < 4; i++)
#pragma unroll
        for (int j = 0; j < 4; j++) acc[i][j] = (f32x4){0.f, 0.f, 0.f, 0.f};

    for (int kt = 0; kt < K; kt += 32) {
        const unsigned short *ah, *al; int lda, kl;
        if (kt < K0) { ah = A0h; al = A0l; lda = lda0; kl = kt; }
        else         { ah = A1h; al = A1l; lda = lda1; kl = kt - K0; }
        __syncthreads();
#pragma unroll
        for (int hh = 0; hh < 2; hh++) {
            size_t arow = (size_t)(m0 + hh * 64 + srow);
            size_t brow = (size_t)(n0 + hh * 64 + srow);
            char* dA = (char*)lAh + hh * 4096 + w * 1024;
            char* dAl = (char*)lAl + hh * 4096 + w * 1024;
            char* dB = (char*)lBh + hh * 4096 + w * 1024;
            char* dBl = (char*)lBl + hh * 4096 + w * 1024;
            gload16(ah + arow * lda + kl + skoff, dA);
            gload16(al + arow * lda + kl + skoff, dAl);
            gload16(Bh + brow * K + kt + skoff, dB);
            gload16(Bl + brow * K + kt + skoff, dBl);
        }
        __syncthreads();

        short8 fah[4], fal[4], fbh[4], fbl[4];
#pragma unroll
        for (int mf = 0; mf < 4; mf++) {
            int row = wm * 64 + mf * 16 + lr;
            fah[mf] = *(const short8*)&lAh[row * 32 + lk * 8];
            fal[mf] = *(const short8*)&lAl[row * 32 + lk * 8];
        }
#pragma unroll
        for (int nf = 0; nf < 4; nf++) {
            int row = wn * 64 + nf * 16 + lr;
            fbh[nf] = *(const short8*)&lBh[row * 32 + lk * 8];
            fbl[nf] = *(const short8*)&lBl[row * 32 + lk * 8];
        }
#pragma unroll
        for (int mf = 0; mf < 4; mf++)
#pragma unroll
            for (int nf = 0; nf < 4; nf++) {
                acc[mf][nf] = __builtin_amdgcn_mfma_f32_16x16x32_bf16(
                    fah[mf], fbh[nf], acc[mf][nf], 0, 0, 0);
                acc[mf][nf] = __builtin_amdgcn_mfma_f32_16x16x32_bf16(
                    fah[mf], fbl[nf], acc[mf][nf], 0, 0, 0);
                acc[mf][nf] = __builtin_amdgcn_mfma_f32_16x16x32_bf16(
                    fal[mf], fbh[nf], acc[mf][nf], 0, 0, 0);
            }
    }

#pragma unroll
    for (int nf = 0; nf < 4; nf++) {
        int gcol = n0 + wn * 64 + nf * 16 + lr;
        float bv = bias[gcol];
#pragma unroll
        for (int mf = 0; mf < 4; mf++) {
            int grow = m0 + wm * 64 + mf * 16 + lk * 4;
#pragma unroll
            for (int q = 0; q < 4; q++)
                out[(size_t)(grow + q) * 512 + gcol] = acc[mf][nf][q] + bv;
        }
    }
}

// ---------------- LSTM scan: whh in VGPRs, 256 blocks x 2 rows ----------------
// OUTMODE 0: chunk-local bf16 hi/lo [tt*512+b][128]; 1: global-t bf16 hi/lo;
// OUTMODE 2: f32 h at t==99 -> outF[b][128]
template <int OUTMODE, int REV>
__global__ __launch_bounds__(512) void lstm_scan(
    const float* __restrict__ Xpre, const float* __restrict__ whh,
    float* __restrict__ state_h, float* __restrict__ state_c,
    unsigned short* __restrict__ outH, unsigned short* __restrict__ outL,
    float* __restrict__ outF, int t0, int TC)
{
    int r0 = blockIdx.x * 2;
    int g = threadIdx.x;

    __shared__ __align__(16) float h_lds[2][128];
    __shared__ float c_lds[2][128];
    __shared__ float g_lds[2][512];

    float w[128];
#pragma unroll
    for (int k = 0; k < 128; k += 4) {
        float4 wv = *(const float4*)&whh[(size_t)g * 128 + k];
        w[k] = wv.x; w[k + 1] = wv.y; w[k + 2] = wv.z; w[k + 3] = wv.w;
    }
    if (g < 256) {
        int r = g >> 7, j = g & 127;
        h_lds[r][j] = state_h[(size_t)(r0 + r) * 128 + j];
        c_lds[r][j] = state_c[(size_t)(r0 + r) * 128 + j];
    }
    __syncthreads();

    for (int s = 0; s < TC; s++) {
        int tt = REV ? (TC - 1 - s) : s;
        float acc0 = Xpre[((size_t)tt * 512 + r0 + 0) * 512 + g];
        float acc1 = Xpre[((size_t)tt * 512 + r0 + 1) * 512 + g];
#pragma unroll
        for (int k = 0; k < 128; k += 4) {
            float4 h0 = *(const float4*)&h_lds[0][k];
            float4 h1 = *(const float4*)&h_lds[1][k];
            acc0 += w[k] * h0.x + w[k + 1] * h0.y + w[k + 2] * h0.z + w[k + 3] * h0.w;
            acc1 += w[k] * h1.x + w[k + 1] * h1.y + w[k + 2] * h1.z + w[k + 3] * h1.w;
        }
        g_lds[0][g] = acc0;
        g_lds[1][g] = acc1;
        __syncthreads();
        if (g < 256) {
            int r = g >> 7, j = g & 127;
            float gi = sigmoidf_(g_lds[r][j]);
            float gf = sigmoidf_(g_lds[r][128 + j]);
            float gg = tanhf_(g_lds[r][256 + j]);
            float go = sigmoidf_(g_lds[r][384 + j]);
            float c = gf * c_lds[r][j] + gi * gg;
            c_lds[r][j] = c;
            float h = go * tanhf_(c);
            h_lds[r][j] = h;
            if (OUTMODE == 0 || OUTMODE == 1) {
                size_t idx = (OUTMODE == 0)
                    ? ((size_t)tt * 512 + r0 + r) * 128 + j
                    : ((size_t)(t0 + tt) * 512 + r0 + r) * 128 + j;
                unsigned short hi = f2bf_rn(h);
                outH[idx] = hi;
                outL[idx] = f2bf_rn(h - bf2f(hi));
            } else if (t0 + tt == T_STEPS - 1) {
                outF[(size_t)(r0 + r) * 128 + j] = h;
            }
        }
        __syncthreads();
    }

    if (g < 256) {
        int r = g >> 7, j = g & 127;
        state_h[(size_t)(r0 + r) * 128 + j] = h_lds[r][j];
        state_c[(size_t)(r0 + r) * 128 + j] = c_lds[r][j];
    }
}

// ---------------- final: layer1-bwd single step + FC head ----------------
__global__ __launch_bounds__(128) void final_kernel(
    const float* __restrict__ h1f, const float* __restrict__ xp1b,
    const float* __restrict__ fc1w, const float* __restrict__ fc1b,
    const float* __restrict__ fc2w, const float* __restrict__ fc2b,
    float* __restrict__ out)
{
    int b = blockIdx.x, tid = threadIdx.x;
    __shared__ float last[256];
    __shared__ float f1[64];
    {
        int j = tid;
        float gi = sigmoidf_(xp1b[(size_t)b * 512 + j]);
        float gg = tanhf_(xp1b[(size_t)b * 512 + 256 + j]);
        float go = sigmoidf_(xp1b[(size_t)b * 512 + 384 + j]);
        float c = gi * gg;                  // h0 = c0 = 0
        last[128 + j] = go * tanhf_(c);
        last[j] = h1f[(size_t)b * 128 + j];
    }
    __syncthreads();
    if (tid < 64) {
        float a = fc1b[tid];
        for (int k = 0; k < 256; k++) a += last[k] * fc1w[tid * 256 + k];
        f1[tid] = a > 0.f ? a : 0.f;
    }
    __syncthreads();
    if (tid < 2) {
        float a = fc2b[tid];
        for (int k = 0; k < 64; k++) a += f1[k] * fc2w[tid * 64 + k];
        out[b * 2 + tid] = a;
    }
}

extern "C" void kernel_launch(void* const* d_in, const int* in_sizes, int n_in,
                              void* d_out, int out_size, void* d_ws, size_t ws_size,
                              hipStream_t stream)
{
    const float* x     = (const float*)d_in[0];
    const float* c1w   = (const float*)d_in[1];
    const float* c1b   = (const float*)d_in[2];
    const float* g1    = (const float*)d_in[3];
    const float* b1    = (const float*)d_in[4];
    const float* m1    = (const float*)d_in[5];
    const float* v1    = (const float*)d_in[6];
    const float* c2w   = (const float*)d_in[7];
    const float* c2b   = (const float*)d_in[8];
    const float* g2    = (const float*)d_in[9];
    const float* b2    = (const float*)d_in[10];
    const float* m2    = (const float*)d_in[11];
    const float* v2    = (const float*)d_in[12];
    const float* wih0f = (const float*)d_in[13];
    const float* whh0f = (const float*)d_in[14];
    const float* bih0f = (const float*)d_in[15];
    const float* bhh0f = (const float*)d_in[16];
    const float* wih0b = (const float*)d_in[17];
    const float* whh0b = (const float*)d_in[18];
    const float* bih0b = (const float*)d_in[19];
    const float* bhh0b = (const float*)d_in[20];
    const float* wih1f = (const float*)d_in[21];
    const float* whh1f = (const float*)d_in[22];
    const float* bih1f = (const float*)d_in[23];
    const float* bhh1f = (const float*)d_in[24];
    const float* wih1b = (const float*)d_in[25];
    const float* bih1b = (const float*)d_in[27];
    const float* bhh1b = (const float*)d_in[28];
    const float* fc1w  = (const float*)d_in[29];
    const float* fc1b  = (const float*)d_in[30];
    const float* fc2w  = (const float*)d_in[31];
    const float* fc2b  = (const float*)d_in[32];

    float* ws  = (float*)d_ws;
    unsigned short* wsH = (unsigned short*)d_ws;
    float* out = (float*)d_out;

    // pick largest time-chunk that fits ws
    const int cands[9] = {100, 50, 25, 20, 10, 5, 4, 2, 1};
    int TC = 1;
    size_t avail = ws_size / 4;
    for (int i = 0; i < 9; i++) {
        size_t need = (size_t)OFF_DYN + (size_t)cands[i] * 557056u;
        if (need <= avail) { TC = cands[i]; break; }
    }
    int NCH = T_STEPS / TC;

    unsigned short* cnnH = wsH + (size_t)OFF_DYN * 2;       // [TC*512][448] bf16
    unsigned short* cnnL = cnnH + (size_t)TC * 229376;
    float* xprebuf = ws + OFF_DYN + (size_t)TC * 229376;    // [TC*512][512] f32
    unsigned short* seqfH = (unsigned short*)(xprebuf + (size_t)TC * 262144);
    unsigned short* seqfL = seqfH + (size_t)TC * 65536;
    unsigned short* seq1bH = wsH + (size_t)OFF_SEQ1BH * 2;  // [100*512][128] bf16
    unsigned short* seq1bL = wsH + (size_t)OFF_SEQ1BL * 2;

    const unsigned short* W0FH = wsH + (size_t)OFF_W0FH * 2;
    const unsigned short* W0FL = wsH + (size_t)OFF_W0FL * 2;
    const unsigned short* W0BH = wsH + (size_t)OFF_W0BH * 2;
    const unsigned short* W0BL = wsH + (size_t)OFF_W0BL * 2;
    const unsigned short* W1FH = wsH + (size_t)OFF_W1FH * 2;
    const unsigned short* W1FL = wsH + (size_t)OFF_W1FL * 2;
    const unsigned short* W1BH = wsH + (size_t)OFF_W1BH * 2;
    const unsigned short* W1BL = wsH + (size_t)OFF_W1BL * 2;

    // 1. prep
    hipLaunchKernelGGL(prep_kernel, dim3(7241), dim3(256), 0, stream,
                       c1w, c1b, g1, b1, m1, v1, c2w, c2b, g2, b2, m2, v2,
                       wih0f, wih0b, wih1f, wih1b,
                       bih0f, bhh0f, bih0b, bhh0b, bih1f, bhh1f, bih1b, bhh1b, ws);

    // 2. phase 1: layer-0 backward, chunks in reverse time order
    for (int ci = NCH - 1; ci >= 0; ci--) {
        int t0 = ci * TC;
        hipLaunchKernelGGL(cnn_kernel, dim3(TC * 32), dim3(256), 0, stream,
                           x, ws, cnnH, cnnL, t0);
        hipLaunchKernelGGL(mgemm, dim3(TC * 4, 4), dim3(256), 0, stream,
                           cnnH, cnnL, 448, 448, cnnH, cnnL, 448,
                           W0BH, W0BL, ws + OFF_BIASL0 + 512, xprebuf, 448);
        hipLaunchKernelGGL((lstm_scan<1, 1>), dim3(256), dim3(512), 0, stream,
                           xprebuf, whh0b,
                           ws + OFF_STATE, ws + OFF_STATE + 65536,
                           seq1bH, seq1bL, (float*)nullptr, t0, TC);
    }

    // 3. phase 2: layer-0 forward + layer-1 forward, fused per chunk
    for (int ci = 0; ci < NCH; ci++) {
        int t0 = ci * TC;
        hipLaunchKernelGGL(cnn_kernel, dim3(TC * 32), dim3(256), 0, stream,
                           x, ws, cnnH, cnnL, t0);
        hipLaunchKernelGGL(mgemm, dim3(TC * 4, 4), dim3(256), 0, stream,
                           cnnH, cnnL, 448, 448, cnnH, cnnL, 448,
                           W0FH, W0FL, ws + OFF_BIASL0, xprebuf, 448);
        hipLaunchKernelGGL((lstm_scan<0, 0>), dim3(256), dim3(512), 0, stream,
                           xprebuf, whh0f,
                           ws + OFF_STATE + 131072, ws + OFF_STATE + 196608,
                           seqfH, seqfL, (float*)nullptr, t0, TC);
        hipLaunchKernelGGL(mgemm, dim3(TC * 4, 4), dim3(256), 0, stream,
                           seqfH, seqfL, 128, 128,
                           seq1bH + (size_t)t0 * 65536, seq1bL + (size_t)t0 * 65536, 128,
                           W1FH, W1FL, ws + OFF_BIAS1F, xprebuf, 256);
        hipLaunchKernelGGL((lstm_scan<2, 0>), dim3(256), dim3(512), 0, stream,
                           xprebuf, whh1f,
                           ws + OFF_STATE + 262144, ws + OFF_STATE + 327680,
                           (unsigned short*)nullptr, (unsigned short*)nullptr,
                           ws + OFF_H1F, t0, TC);
    }

    // 4. layer-1 backward single step (t=99)
    hipLaunchKernelGGL(mgemm, dim3(4, 4), dim3(256), 0, stream,
                       seqfH + (size_t)(TC - 1) * 65536, seqfL + (size_t)(TC - 1) * 65536,
                       128, 128,
                       seq1bH + (size_t)99 * 65536, seq1bL + (size_t)99 * 65536, 128,
                       W1BH, W1BL, ws + OFF_BIAS1B, ws + OFF_XP1B, 256);

    // 5. final FC head
    hipLaunchKernelGGL(final_kernel, dim3(512), dim3(128), 0, stream,
                       ws + OFF_H1F, ws + OFF_XP1B, fc1w, fc1b, fc2w, fc2b, out);

    (void)in_sizes; (void)n_in; (void)out_size; (void)ws_size;
}